// Round 14
// baseline (113.272 us; speedup 1.0000x reference)
//
#include <hip/hip_runtime.h>
#include <hip/hip_bf16.h>
#include <stdint.h>

#define NN   50000
#define NE   800000
#define INF_ 16
#define OUTF 32
#define HIDN 25
#define NC   10
#define QG   2048                 // edge_attr quantization levels
#define QPB  16                   // q values per prep_G block
#define DPB  16                   // dsts per bucket
#define NB   3125                 // 50000/16
#define EPB  16384                // edges per sort block
#define NBLK 49                   // ceil(NE/EPB)
#define ASTR 33                   // padded agg row stride
#define ECAP 768                  // LDS-staged edges per bucket (mean 256)
#define SCH  13                   // ceil(NB/256) for in-LDS scan

#define SENT 0x007FFFFFu          // map_f(-inf)

#define GB_PREP 128               // prep_G blocks
#define GB_HIST NBLK              // hist blocks
#define GB_XH   391               // ceil(NN*INF_/2/1024), 4 pairs/thread

typedef _Float16 f16x2 __attribute__((ext_vector_type(2)));

__device__ __forceinline__ uint32_t map_f(float f) {
    uint32_t b = __float_as_uint(f);
    return (b & 0x80000000u) ? ~b : (b | 0x80000000u);
}
__device__ __forceinline__ float unmap_f(uint32_t u) {
    return (u & 0x80000000u) ? __uint_as_float(u ^ 0x80000000u)
                             : __uint_as_float(~u);
}

__device__ __forceinline__ float dot2f(uint32_t g, uint32_t xb, float acc) {
#if __has_builtin(__builtin_amdgcn_fdot2)
    union { uint32_t u; f16x2 h; } ug, ux;
    ug.u = g; ux.u = xb;
    return __builtin_amdgcn_fdot2(ug.h, ux.h, acc, false);
#else
    union { uint32_t u; _Float16 h[2]; } ug, ux;
    ug.u = g; ux.u = xb;
    return fmaf((float)ug.h[0], (float)ux.h[0],
                fmaf((float)ug.h[1], (float)ux.h[1], acc));
#endif
}

// ---------- merged prep: [0,128) G2; [128,177) hist H[blk][bin]; rest xh ----------
__global__ __launch_bounds__(256) void prep_k(const float* __restrict__ w1,
                                              const float* __restrict__ b1,
                                              const float* __restrict__ w2,
                                              const float* __restrict__ b2,
                                              const float* __restrict__ x,
                                              const int* __restrict__ ei,
                                              uint32_t* __restrict__ G2,
                                              uint32_t* __restrict__ xh,
                                              uint32_t* __restrict__ H) {
    __shared__ union {
        struct { float w2s[HIDN * 512]; float b2s[512]; float hs[QPB][HIDN]; } g;
        uint32_t hloc[NB];
    } sm;

    const int b = blockIdx.x;
    if (b < GB_PREP) {
        for (int i = threadIdx.x; i < HIDN * 512; i += 256) sm.g.w2s[i] = w2[i];
        for (int i = threadIdx.x; i < 512; i += 256) sm.g.b2s[i] = b2[i];
        for (int i = threadIdx.x; i < QPB * HIDN; i += 256) {
            int qq = i / HIDN, k = i - qq * HIDN;
            float aq = (b * QPB + qq + 0.5f) * (1.0f / (float)QG);
            sm.g.hs[qq][k] = fmaxf(fmaf(aq, w1[k], b1[k]), 0.f);
        }
        __syncthreads();
        for (int qq = 0; qq < QPB; ++qq) {
            const int q = b * QPB + qq;
            int e = threadIdx.x;
            int ip = e >> 5, o = e & 31;
            float g0 = sm.g.b2s[(2 * ip) * OUTF + o];
            float g1 = sm.g.b2s[(2 * ip + 1) * OUTF + o];
#pragma unroll
            for (int k = 0; k < HIDN; ++k) {
                float h = sm.g.hs[qq][k];
                g0 = fmaf(h, sm.g.w2s[k * 512 + (2 * ip) * OUTF + o], g0);
                g1 = fmaf(h, sm.g.w2s[k * 512 + (2 * ip + 1) * OUTF + o], g1);
            }
            union { uint32_t u; f16x2 h2; } p;
            p.h2[0] = (_Float16)g0;
            p.h2[1] = (_Float16)g1;
            G2[(size_t)q * 256 + e] = p.u;
        }
    } else if (b < GB_PREP + GB_HIST) {
        const int blk = b - GB_PREP;
        for (int i = threadIdx.x; i < NB; i += 256) sm.hloc[i] = 0;
        __syncthreads();
        const int base = blk * EPB;
        for (int j = 0; j < EPB; j += 256) {
            int e = base + j + threadIdx.x;
            if (e < NE) atomicAdd(&sm.hloc[ei[NE + e] >> 4], 1u);
        }
        __syncthreads();
        for (int i = threadIdx.x; i < NB; i += 256)
            H[(size_t)blk * NB + i] = sm.hloc[i];
    } else {
        // x -> packed f16 pairs, 4 pairs (8 floats) per thread
        int t4 = ((b - GB_PREP - GB_HIST) * 256 + threadIdx.x) * 4;
        if (t4 < NN * INF_ / 2) {
            const float4* xp = reinterpret_cast<const float4*>(x) + (t4 >> 1);
            float4 va = xp[0];
            float4 vb = xp[1];
            union { uint32_t u[4]; f16x2 h[4]; } p;
            p.h[0][0] = (_Float16)va.x; p.h[0][1] = (_Float16)va.y;
            p.h[1][0] = (_Float16)va.z; p.h[1][1] = (_Float16)va.w;
            p.h[2][0] = (_Float16)vb.x; p.h[2][1] = (_Float16)vb.y;
            p.h[3][0] = (_Float16)vb.z; p.h[3][1] = (_Float16)vb.w;
            *reinterpret_cast<uint4*>(xh + t4) = make_uint4(p.u[0], p.u[1], p.u[2], p.u[3]);
        }
    }
}

// ---------- scatter: per-block prefix + bstart scan (from H) + scatter ----------
__global__ __launch_bounds__(256) void scatter_k(const int* __restrict__ ei,
                                                 const float* __restrict__ ea,
                                                 const uint32_t* __restrict__ H,
                                                 uint32_t* __restrict__ bstart,
                                                 uint32_t* __restrict__ sorted) {
    __shared__ uint32_t cur[NB];
    __shared__ uint32_t pref[NB];
    __shared__ uint32_t bst[NB + 1];
    __shared__ uint32_t part[256];
    const int myblk = blockIdx.x;
    const int tid = threadIdx.x;

    for (int bin = tid; bin < NB; bin += 256) {
        uint32_t p = 0, tt = 0;
        for (int b = 0; b < NBLK; ++b) {
            uint32_t v = H[(size_t)b * NB + bin];
            tt += v;
            if (b < myblk) p += v;
        }
        pref[bin] = p;
        bst[bin] = tt;           // tot, scanned in place below
        cur[bin] = 0;
    }
    __syncthreads();

    // exclusive scan of bst[0..NB)
    uint32_t loc[SCH];
    uint32_t s = 0;
#pragma unroll
    for (int j = 0; j < SCH; ++j) {
        int idx = tid * SCH + j;
        uint32_t v = (idx < NB) ? bst[idx] : 0;
        loc[j] = s;
        s += v;
    }
    part[tid] = s;
    __syncthreads();
    for (int off = 1; off < 256; off <<= 1) {
        uint32_t add = (tid >= off) ? part[tid - off] : 0;
        __syncthreads();
        part[tid] += add;
        __syncthreads();
    }
    uint32_t base = (tid > 0) ? part[tid - 1] : 0;
    __syncthreads();
#pragma unroll
    for (int j = 0; j < SCH; ++j) {
        int idx = tid * SCH + j;
        if (idx < NB) bst[idx] = base + loc[j];
    }
    if (tid == 255) bst[NB] = part[255];
    __syncthreads();

    if (myblk == 0)
        for (int i = tid; i <= NB; i += 256) bstart[i] = bst[i];

    const int ebase = myblk * EPB;
    for (int j = 0; j < EPB; j += 256) {
        int e = ebase + j + tid;
        if (e < NE) {
            int sn = ei[e];
            int d  = ei[NE + e];
            float a = ea[e];
            int q = (int)(a * (float)QG);
            q = q < 0 ? 0 : (q > QG - 1 ? QG - 1 : q);
            int bin = d >> 4;
            uint32_t r = atomicAdd(&cur[bin], 1u);
            uint32_t pos = bst[bin] + pref[bin] + r;
            sorted[pos] = ((uint32_t)q << 21) | ((uint32_t)sn << 5)
                        | (uint32_t)(d & 15);
        }
    }
}

// ---------- fused: 8 lanes/edge, dot2, unroll-2, LDS max-agg, epilogue ----------
__global__ __launch_bounds__(256) void fused_k(const uint32_t* __restrict__ sorted,
                                               const uint32_t* __restrict__ bstart,
                                               const float* __restrict__ x,
                                               const uint32_t* __restrict__ xh,
                                               const uint32_t* __restrict__ G2,
                                               const float* __restrict__ root,
                                               const float* __restrict__ bias,
                                               const float* __restrict__ fcw,
                                               const float* __restrict__ fcb,
                                               float* __restrict__ out) {
    __shared__ uint32_t ebuf[ECAP];              // 3 KB staged edge records
    __shared__ uint32_t agg[DPB * ASTR];         // 2.1 KB
    __shared__ float rs[INF_ * OUTF];
    __shared__ float bs[OUTF];
    __shared__ float fws[OUTF * NC];
    __shared__ float fbs[NC];

    const int bin  = blockIdx.x;
    const int segs = (int)bstart[bin];
    const int cnt  = (int)bstart[bin + 1] - segs;
    const int scnt = cnt < ECAP ? cnt : ECAP;

    for (int i = threadIdx.x; i < scnt; i += 256) ebuf[i] = sorted[segs + i];
    for (int i = threadIdx.x; i < DPB * ASTR; i += 256) agg[i] = SENT;
    for (int i = threadIdx.x; i < INF_ * OUTF; i += 256) rs[i] = root[i];
    if (threadIdx.x < OUTF) bs[threadIdx.x] = bias[threadIdx.x];
    for (int i = threadIdx.x; i < OUTF * NC; i += 256) fws[i] = fcw[i];
    if (threadIdx.x < NC) fbs[threadIdx.x] = fcb[threadIdx.x];
    __syncthreads();

    const int c   = threadIdx.x & 7;             // owns channels 4c..4c+3
    const int grp = threadIdx.x >> 3;            // 0..31 edge groups

#define EDGE_LOAD(rec, hx0, hx1, gq)                                            \
    int src_ = ((rec) >> 5) & 0xFFFF;                                           \
    int q_ = (rec) >> 21;                                                       \
    const uint4* xp_ = reinterpret_cast<const uint4*>(xh) + src_ * 2;           \
    hx0 = xp_[0]; hx1 = xp_[1];                                                 \
    gq = reinterpret_cast<const uint4*>(G2) + (size_t)q_ * 64 + c;

#define EDGE_DOT(hx0, hx1, gq, p0, p1, p2, p3)                                  \
    {                                                                           \
        uint4 g0 = gq[0],  g1 = gq[8],  g2 = gq[16], g3 = gq[24];               \
        uint4 g4 = gq[32], g5 = gq[40], g6 = gq[48], g7 = gq[56];               \
        p0 = dot2f(g0.x, hx0.x, p0); p1 = dot2f(g0.y, hx0.x, p1);               \
        p2 = dot2f(g0.z, hx0.x, p2); p3 = dot2f(g0.w, hx0.x, p3);               \
        p0 = dot2f(g1.x, hx0.y, p0); p1 = dot2f(g1.y, hx0.y, p1);               \
        p2 = dot2f(g1.z, hx0.y, p2); p3 = dot2f(g1.w, hx0.y, p3);               \
        p0 = dot2f(g2.x, hx0.z, p0); p1 = dot2f(g2.y, hx0.z, p1);               \
        p2 = dot2f(g2.z, hx0.z, p2); p3 = dot2f(g2.w, hx0.z, p3);               \
        p0 = dot2f(g3.x, hx0.w, p0); p1 = dot2f(g3.y, hx0.w, p1);               \
        p2 = dot2f(g3.z, hx0.w, p2); p3 = dot2f(g3.w, hx0.w, p3);               \
        p0 = dot2f(g4.x, hx1.x, p0); p1 = dot2f(g4.y, hx1.x, p1);               \
        p2 = dot2f(g4.z, hx1.x, p2); p3 = dot2f(g4.w, hx1.x, p3);               \
        p0 = dot2f(g5.x, hx1.y, p0); p1 = dot2f(g5.y, hx1.y, p1);               \
        p2 = dot2f(g5.z, hx1.y, p2); p3 = dot2f(g5.w, hx1.y, p3);               \
        p0 = dot2f(g6.x, hx1.z, p0); p1 = dot2f(g6.y, hx1.z, p1);               \
        p2 = dot2f(g6.z, hx1.z, p2); p3 = dot2f(g6.w, hx1.z, p3);               \
        p0 = dot2f(g7.x, hx1.w, p0); p1 = dot2f(g7.y, hx1.w, p1);               \
        p2 = dot2f(g7.z, hx1.w, p2); p3 = dot2f(g7.w, hx1.w, p3);               \
    }

    int it = grp;
    for (; it + 32 < cnt; it += 64) {
        uint32_t recA = (it < ECAP) ? ebuf[it] : sorted[segs + it];
        int itB = it + 32;
        uint32_t recB = (itB < ECAP) ? ebuf[itB] : sorted[segs + itB];
        uint4 ax0, ax1, bx0, bx1;
        const uint4 *gqA, *gqB;
        { EDGE_LOAD(recA, ax0, ax1, gqA) }
        int dbA = recA & 15;
        { EDGE_LOAD(recB, bx0, bx1, gqB) }
        int dbB = recB & 15;

        float a0 = 0.f, a1 = 0.f, a2 = 0.f, a3 = 0.f;
        float b0 = 0.f, b1 = 0.f, b2 = 0.f, b3 = 0.f;
        EDGE_DOT(ax0, ax1, gqA, a0, a1, a2, a3)
        EDGE_DOT(bx0, bx1, gqB, b0, b1, b2, b3)

        uint32_t* agA = &agg[dbA * ASTR + c * 4];
        atomicMax(&agA[0], map_f(a0));
        atomicMax(&agA[1], map_f(a1));
        atomicMax(&agA[2], map_f(a2));
        atomicMax(&agA[3], map_f(a3));
        uint32_t* agB = &agg[dbB * ASTR + c * 4];
        atomicMax(&agB[0], map_f(b0));
        atomicMax(&agB[1], map_f(b1));
        atomicMax(&agB[2], map_f(b2));
        atomicMax(&agB[3], map_f(b3));
    }
    if (it < cnt) {
        uint32_t recA = (it < ECAP) ? ebuf[it] : sorted[segs + it];
        uint4 ax0, ax1;
        const uint4* gqA;
        { EDGE_LOAD(recA, ax0, ax1, gqA) }
        int dbA = recA & 15;
        float a0 = 0.f, a1 = 0.f, a2 = 0.f, a3 = 0.f;
        EDGE_DOT(ax0, ax1, gqA, a0, a1, a2, a3)
        uint32_t* agA = &agg[dbA * ASTR + c * 4];
        atomicMax(&agA[0], map_f(a0));
        atomicMax(&agA[1], map_f(a1));
        atomicMax(&agA[2], map_f(a2));
        atomicMax(&agA[3], map_f(a3));
    }
    __syncthreads();

    // epilogue: 16 dsts x (8 lanes x 4 channels); threads 128..255 idle
    {
        const int li8 = threadIdx.x & 7;
        const int dl  = threadIdx.x >> 3;        // 0..31, valid < DPB
        const int n   = bin * DPB + dl;
        if (dl < DPB && n < NN) {
            const uint32_t* ar = &agg[dl * ASTR + li8 * 4];
            float av[4];
#pragma unroll
            for (int qq = 0; qq < 4; ++qq) {
                uint32_t u = ar[qq];
                av[qq] = (u == SENT) ? 0.f : unmap_f(u);
            }
            const float* xr = x + (size_t)n * INF_;
            float4 xa = *reinterpret_cast<const float4*>(xr);
            float4 xb = *reinterpret_cast<const float4*>(xr + 4);
            float4 xc = *reinterpret_cast<const float4*>(xr + 8);
            float4 xd = *reinterpret_cast<const float4*>(xr + 12);
            float xv[INF_] = {xa.x,xa.y,xa.z,xa.w, xb.x,xb.y,xb.z,xb.w,
                              xc.x,xc.y,xc.z,xc.w, xd.x,xd.y,xd.z,xd.w};
            float ov[4];
#pragma unroll
            for (int qq = 0; qq < 4; ++qq) {
                int oc = li8 * 4 + qq;
                float tv = av[qq] + bs[oc];
#pragma unroll
                for (int i = 0; i < INF_; ++i) tv = fmaf(xv[i], rs[i * OUTF + oc], tv);
                ov[qq] = (tv > 0.f) ? tv : expm1f(tv);   // ELU alpha=1
            }
            float lg[NC];
#pragma unroll
            for (int cc = 0; cc < NC; ++cc) {
                float tv = 0.f;
#pragma unroll
                for (int qq = 0; qq < 4; ++qq) tv = fmaf(ov[qq], fws[(li8 * 4 + qq) * NC + cc], tv);
                lg[cc] = tv;
            }
#pragma unroll
            for (int m = 1; m <= 4; m <<= 1) {
#pragma unroll
                for (int cc = 0; cc < NC; ++cc) lg[cc] += __shfl_xor(lg[cc], m);
            }
#pragma unroll
            for (int cc = 0; cc < NC; ++cc) lg[cc] += fbs[cc];

            float mx = lg[0];
#pragma unroll
            for (int cc = 1; cc < NC; ++cc) mx = fmaxf(mx, lg[cc]);
            float ssum = 0.f;
#pragma unroll
            for (int cc = 0; cc < NC; ++cc) ssum += expf(lg[cc] - mx);
            float lse = mx + logf(ssum);

            float* orow = out + (size_t)n * NC;
            orow[li8] = lg[li8] - lse;
            if (li8 < 2) orow[8 + li8] = lg[8 + li8] - lse;
        }
    }
}

extern "C" void kernel_launch(void* const* d_in, const int* in_sizes, int n_in,
                              void* d_out, int out_size, void* d_ws, size_t ws_size,
                              hipStream_t stream) {
    const float* x    = (const float*)d_in[0];
    const float* ea   = (const float*)d_in[1];
    const int*   ei   = (const int*)d_in[2];
    const float* w1   = (const float*)d_in[3];
    const float* b1   = (const float*)d_in[4];
    const float* w2   = (const float*)d_in[5];
    const float* b2   = (const float*)d_in[6];
    const float* root = (const float*)d_in[7];
    const float* bias = (const float*)d_in[8];
    const float* fcw  = (const float*)d_in[9];
    const float* fcb  = (const float*)d_in[10];
    float* out = (float*)d_out;

    size_t off = 0;
    auto alloc = [&](size_t bytes) {
        void* p = (char*)d_ws + off;
        off += (bytes + 255) & ~(size_t)255;
        return p;
    };
    uint32_t* G2       = (uint32_t*)alloc((size_t)QG * 256 * 4);               // 2 MB
    uint32_t* xh       = (uint32_t*)alloc((size_t)NN * INF_ * 2);              // 1.6 MB
    uint32_t* H        = (uint32_t*)alloc((size_t)NBLK * NB * 4);              // 613 KB
    uint32_t* bstart   = (uint32_t*)alloc((size_t)(NB + 1) * 4);
    uint32_t* sorted   = (uint32_t*)alloc((size_t)NE * 4);                     // 3.2 MB

    prep_k<<<GB_PREP + GB_HIST + GB_XH, 256, 0, stream>>>(w1, b1, w2, b2, x, ei, G2, xh, H);
    scatter_k<<<NBLK, 256, 0, stream>>>(ei, ea, H, bstart, sorted);
    fused_k<<<NB, 256, 0, stream>>>(sorted, bstart, x, xh, G2, root, bias, fcw, fcb, out);
}

// Round 15
// 86.079 us; speedup vs baseline: 1.3159x; 1.3159x over previous
//
#include <hip/hip_runtime.h>
#include <hip/hip_bf16.h>
#include <stdint.h>

#define NN   50000
#define NE   800000
#define INF_ 16
#define OUTF 32
#define HIDN 25
#define NC   10
#define QG   2048                 // edge_attr quantization levels
#define QPB  16                   // q values per prep_G block
#define DPB  16                   // dsts per bucket
#define NB   3125                 // 50000/16
#define EPB  4096                 // edges per sort block
#define NBLK 196                  // ceil(NE/EPB)
#define ASTR 33                   // padded agg row stride
#define ECAP 768                  // LDS-staged edges per bucket (mean 256)
#define SCH  13                   // ceil(NB/256) for binscan

#define SENT 0x007FFFFFu          // map_f(-inf)

#define GB_PREP 128               // prep_G blocks
#define GB_HIST NBLK              // hist blocks
#define GB_XH   391               // ceil(NN*INF_/2/1024), 4 pairs/thread

typedef _Float16 f16x2 __attribute__((ext_vector_type(2)));

__device__ __forceinline__ uint32_t map_f(float f) {
    uint32_t b = __float_as_uint(f);
    return (b & 0x80000000u) ? ~b : (b | 0x80000000u);
}
__device__ __forceinline__ float unmap_f(uint32_t u) {
    return (u & 0x80000000u) ? __uint_as_float(u ^ 0x80000000u)
                             : __uint_as_float(~u);
}

__device__ __forceinline__ float dot2f(uint32_t g, uint32_t xb, float acc) {
#if __has_builtin(__builtin_amdgcn_fdot2)
    union { uint32_t u; f16x2 h; } ug, ux;
    ug.u = g; ux.u = xb;
    return __builtin_amdgcn_fdot2(ug.h, ux.h, acc, false);
#else
    union { uint32_t u; _Float16 h[2]; } ug, ux;
    ug.u = g; ux.u = xb;
    return fmaf((float)ug.h[0], (float)ux.h[0],
                fmaf((float)ug.h[1], (float)ux.h[1], acc));
#endif
}

// ---------- merged prep: [0,128) G2; [128,324) hist H[bin][blk]; rest xh ----------
__global__ __launch_bounds__(256) void prep_k(const float* __restrict__ w1,
                                              const float* __restrict__ b1,
                                              const float* __restrict__ w2,
                                              const float* __restrict__ b2,
                                              const float* __restrict__ x,
                                              const int* __restrict__ ei,
                                              uint32_t* __restrict__ G2,
                                              uint32_t* __restrict__ xh,
                                              uint32_t* __restrict__ H) {
    __shared__ union {
        struct { float w2s[HIDN * 512]; float b2s[512]; float hs[QPB][HIDN]; } g;
        uint32_t hloc[NB];
    } sm;

    const int b = blockIdx.x;
    if (b < GB_PREP) {
        for (int i = threadIdx.x; i < HIDN * 512; i += 256) sm.g.w2s[i] = w2[i];
        for (int i = threadIdx.x; i < 512; i += 256) sm.g.b2s[i] = b2[i];
        for (int i = threadIdx.x; i < QPB * HIDN; i += 256) {
            int qq = i / HIDN, k = i - qq * HIDN;
            float aq = (b * QPB + qq + 0.5f) * (1.0f / (float)QG);
            sm.g.hs[qq][k] = fmaxf(fmaf(aq, w1[k], b1[k]), 0.f);
        }
        __syncthreads();
        for (int qq = 0; qq < QPB; ++qq) {
            const int q = b * QPB + qq;
            int e = threadIdx.x;
            int ip = e >> 5, o = e & 31;
            float g0 = sm.g.b2s[(2 * ip) * OUTF + o];
            float g1 = sm.g.b2s[(2 * ip + 1) * OUTF + o];
#pragma unroll
            for (int k = 0; k < HIDN; ++k) {
                float h = sm.g.hs[qq][k];
                g0 = fmaf(h, sm.g.w2s[k * 512 + (2 * ip) * OUTF + o], g0);
                g1 = fmaf(h, sm.g.w2s[k * 512 + (2 * ip + 1) * OUTF + o], g1);
            }
            union { uint32_t u; f16x2 h2; } p;
            p.h2[0] = (_Float16)g0;
            p.h2[1] = (_Float16)g1;
            G2[(size_t)q * 256 + e] = p.u;
        }
    } else if (b < GB_PREP + GB_HIST) {
        const int blk = b - GB_PREP;
        for (int i = threadIdx.x; i < NB; i += 256) sm.hloc[i] = 0;
        __syncthreads();
        const int base = blk * EPB;
        for (int j = 0; j < EPB; j += 256) {
            int e = base + j + threadIdx.x;
            if (e < NE) atomicAdd(&sm.hloc[ei[NE + e] >> 4], 1u);
        }
        __syncthreads();
        for (int i = threadIdx.x; i < NB; i += 256)
            H[(size_t)i * NBLK + blk] = sm.hloc[i];
    } else {
        // x -> packed f16 pairs, 4 pairs (8 floats) per thread
        int t4 = ((b - GB_PREP - GB_HIST) * 256 + threadIdx.x) * 4;
        if (t4 < NN * INF_ / 2) {
            const float4* xp = reinterpret_cast<const float4*>(x) + (t4 >> 1);
            float4 va = xp[0];
            float4 vb = xp[1];
            union { uint32_t u[4]; f16x2 h[4]; } p;
            p.h[0][0] = (_Float16)va.x; p.h[0][1] = (_Float16)va.y;
            p.h[1][0] = (_Float16)va.z; p.h[1][1] = (_Float16)va.w;
            p.h[2][0] = (_Float16)vb.x; p.h[2][1] = (_Float16)vb.y;
            p.h[3][0] = (_Float16)vb.z; p.h[3][1] = (_Float16)vb.w;
            *reinterpret_cast<uint4*>(xh + t4) = make_uint4(p.u[0], p.u[1], p.u[2], p.u[3]);
        }
    }
}

// ---------- wave per bin: exclusive prefix over blocks via shfl scan ----------
__global__ __launch_bounds__(256) void colsum_k(const uint32_t* __restrict__ H,
                                                uint32_t* __restrict__ Bp,
                                                uint32_t* __restrict__ tot) {
    const int bin  = (blockIdx.x * 256 + threadIdx.x) >> 6;
    const int lane = threadIdx.x & 63;
    if (bin >= NB) return;
    const uint32_t* hr = H + (size_t)bin * NBLK;
    uint32_t* br = Bp + (size_t)bin * NBLK;
    uint32_t carry = 0;
    for (int b0 = 0; b0 < NBLK; b0 += 64) {
        int b = b0 + lane;
        uint32_t v = (b < NBLK) ? hr[b] : 0;
        uint32_t inc = v;
#pragma unroll
        for (int off = 1; off < 64; off <<= 1) {
            uint32_t t = __shfl_up(inc, off);
            if (lane >= off) inc += t;
        }
        if (b < NBLK) br[b] = carry + inc - v;
        carry += __shfl(inc, 63);
    }
    if (lane == 0) tot[bin] = carry;
}

// ---------- exclusive scan of NB bucket totals (single block, chunked) ----------
__global__ __launch_bounds__(256) void binscan_k(const uint32_t* __restrict__ tot,
                                                 uint32_t* __restrict__ bstart) {
    __shared__ uint32_t part[256];
    const int t = threadIdx.x;
    uint32_t loc[SCH];
    uint32_t s = 0;
#pragma unroll
    for (int j = 0; j < SCH; ++j) {
        int idx = t * SCH + j;
        uint32_t v = (idx < NB) ? tot[idx] : 0;
        loc[j] = s;
        s += v;
    }
    part[t] = s;
    __syncthreads();
    for (int off = 1; off < 256; off <<= 1) {
        uint32_t add = (t >= off) ? part[t - off] : 0;
        __syncthreads();
        part[t] += add;
        __syncthreads();
    }
    uint32_t base = (t > 0) ? part[t - 1] : 0;
#pragma unroll
    for (int j = 0; j < SCH; ++j) {
        int idx = t * SCH + j;
        if (idx < NB) bstart[idx] = base + loc[j];
    }
    if (t == 255) bstart[NB] = part[255];
}

// ---------- scatter: small-LDS, Bp/bstart via L2; pack (q11|src16|db5) ----------
__global__ __launch_bounds__(256) void scatter_k(const int* __restrict__ ei,
                                                 const float* __restrict__ ea,
                                                 const uint32_t* __restrict__ Bp,
                                                 const uint32_t* __restrict__ bstart,
                                                 uint32_t* __restrict__ sorted) {
    __shared__ uint32_t cur[NB];                 // 12.5 KB only
    for (int i = threadIdx.x; i < NB; i += 256) cur[i] = 0;
    __syncthreads();
    const int base = blockIdx.x * EPB;
    for (int j = 0; j < EPB; j += 256) {
        int e = base + j + threadIdx.x;
        if (e < NE) {
            int sn = ei[e];
            int d  = ei[NE + e];
            float a = ea[e];
            int q = (int)(a * (float)QG);
            q = q < 0 ? 0 : (q > QG - 1 ? QG - 1 : q);
            int bin = d >> 4;
            uint32_t r = atomicAdd(&cur[bin], 1u);
            uint32_t pos = bstart[bin] + Bp[(size_t)bin * NBLK + blockIdx.x] + r;
            sorted[pos] = ((uint32_t)q << 21) | ((uint32_t)sn << 5)
                        | (uint32_t)(d & 15);
        }
    }
}

// ---------- fused: 8 lanes/edge, dot2, unroll-2, LDS max-agg, epilogue ----------
__global__ __launch_bounds__(256) void fused_k(const uint32_t* __restrict__ sorted,
                                               const uint32_t* __restrict__ bstart,
                                               const float* __restrict__ x,
                                               const uint32_t* __restrict__ xh,
                                               const uint32_t* __restrict__ G2,
                                               const float* __restrict__ root,
                                               const float* __restrict__ bias,
                                               const float* __restrict__ fcw,
                                               const float* __restrict__ fcb,
                                               float* __restrict__ out) {
    __shared__ uint32_t ebuf[ECAP];              // 3 KB staged edge records
    __shared__ uint32_t agg[DPB * ASTR];         // 2.1 KB
    __shared__ float rs[INF_ * OUTF];
    __shared__ float bs[OUTF];
    __shared__ float fws[OUTF * NC];
    __shared__ float fbs[NC];

    const int bin  = blockIdx.x;
    const int segs = (int)bstart[bin];
    const int cnt  = (int)bstart[bin + 1] - segs;
    const int scnt = cnt < ECAP ? cnt : ECAP;

    for (int i = threadIdx.x; i < scnt; i += 256) ebuf[i] = sorted[segs + i];
    for (int i = threadIdx.x; i < DPB * ASTR; i += 256) agg[i] = SENT;
    for (int i = threadIdx.x; i < INF_ * OUTF; i += 256) rs[i] = root[i];
    if (threadIdx.x < OUTF) bs[threadIdx.x] = bias[threadIdx.x];
    for (int i = threadIdx.x; i < OUTF * NC; i += 256) fws[i] = fcw[i];
    if (threadIdx.x < NC) fbs[threadIdx.x] = fcb[threadIdx.x];
    __syncthreads();

    const int c   = threadIdx.x & 7;             // owns channels 4c..4c+3
    const int grp = threadIdx.x >> 3;            // 0..31 edge groups

#define EDGE_LOAD(rec, hx0, hx1, gq)                                            \
    int src_ = ((rec) >> 5) & 0xFFFF;                                           \
    int q_ = (rec) >> 21;                                                       \
    const uint4* xp_ = reinterpret_cast<const uint4*>(xh) + src_ * 2;           \
    hx0 = xp_[0]; hx1 = xp_[1];                                                 \
    gq = reinterpret_cast<const uint4*>(G2) + (size_t)q_ * 64 + c;

#define EDGE_DOT(hx0, hx1, gq, p0, p1, p2, p3)                                  \
    {                                                                           \
        uint4 g0 = gq[0],  g1 = gq[8],  g2 = gq[16], g3 = gq[24];               \
        uint4 g4 = gq[32], g5 = gq[40], g6 = gq[48], g7 = gq[56];               \
        p0 = dot2f(g0.x, hx0.x, p0); p1 = dot2f(g0.y, hx0.x, p1);               \
        p2 = dot2f(g0.z, hx0.x, p2); p3 = dot2f(g0.w, hx0.x, p3);               \
        p0 = dot2f(g1.x, hx0.y, p0); p1 = dot2f(g1.y, hx0.y, p1);               \
        p2 = dot2f(g1.z, hx0.y, p2); p3 = dot2f(g1.w, hx0.y, p3);               \
        p0 = dot2f(g2.x, hx0.z, p0); p1 = dot2f(g2.y, hx0.z, p1);               \
        p2 = dot2f(g2.z, hx0.z, p2); p3 = dot2f(g2.w, hx0.z, p3);               \
        p0 = dot2f(g3.x, hx0.w, p0); p1 = dot2f(g3.y, hx0.w, p1);               \
        p2 = dot2f(g3.z, hx0.w, p2); p3 = dot2f(g3.w, hx0.w, p3);               \
        p0 = dot2f(g4.x, hx1.x, p0); p1 = dot2f(g4.y, hx1.x, p1);               \
        p2 = dot2f(g4.z, hx1.x, p2); p3 = dot2f(g4.w, hx1.x, p3);               \
        p0 = dot2f(g5.x, hx1.y, p0); p1 = dot2f(g5.y, hx1.y, p1);               \
        p2 = dot2f(g5.z, hx1.y, p2); p3 = dot2f(g5.w, hx1.y, p3);               \
        p0 = dot2f(g6.x, hx1.z, p0); p1 = dot2f(g6.y, hx1.z, p1);               \
        p2 = dot2f(g6.z, hx1.z, p2); p3 = dot2f(g6.w, hx1.z, p3);               \
        p0 = dot2f(g7.x, hx1.w, p0); p1 = dot2f(g7.y, hx1.w, p1);               \
        p2 = dot2f(g7.z, hx1.w, p2); p3 = dot2f(g7.w, hx1.w, p3);               \
    }

    int it = grp;
    for (; it + 32 < cnt; it += 64) {
        uint32_t recA = (it < ECAP) ? ebuf[it] : sorted[segs + it];
        int itB = it + 32;
        uint32_t recB = (itB < ECAP) ? ebuf[itB] : sorted[segs + itB];
        uint4 ax0, ax1, bx0, bx1;
        const uint4 *gqA, *gqB;
        { EDGE_LOAD(recA, ax0, ax1, gqA) }
        int dbA = recA & 15;
        { EDGE_LOAD(recB, bx0, bx1, gqB) }
        int dbB = recB & 15;

        float a0 = 0.f, a1 = 0.f, a2 = 0.f, a3 = 0.f;
        float b0 = 0.f, b1 = 0.f, b2 = 0.f, b3 = 0.f;
        EDGE_DOT(ax0, ax1, gqA, a0, a1, a2, a3)
        EDGE_DOT(bx0, bx1, gqB, b0, b1, b2, b3)

        uint32_t* agA = &agg[dbA * ASTR + c * 4];
        atomicMax(&agA[0], map_f(a0));
        atomicMax(&agA[1], map_f(a1));
        atomicMax(&agA[2], map_f(a2));
        atomicMax(&agA[3], map_f(a3));
        uint32_t* agB = &agg[dbB * ASTR + c * 4];
        atomicMax(&agB[0], map_f(b0));
        atomicMax(&agB[1], map_f(b1));
        atomicMax(&agB[2], map_f(b2));
        atomicMax(&agB[3], map_f(b3));
    }
    if (it < cnt) {
        uint32_t recA = (it < ECAP) ? ebuf[it] : sorted[segs + it];
        uint4 ax0, ax1;
        const uint4* gqA;
        { EDGE_LOAD(recA, ax0, ax1, gqA) }
        int dbA = recA & 15;
        float a0 = 0.f, a1 = 0.f, a2 = 0.f, a3 = 0.f;
        EDGE_DOT(ax0, ax1, gqA, a0, a1, a2, a3)
        uint32_t* agA = &agg[dbA * ASTR + c * 4];
        atomicMax(&agA[0], map_f(a0));
        atomicMax(&agA[1], map_f(a1));
        atomicMax(&agA[2], map_f(a2));
        atomicMax(&agA[3], map_f(a3));
    }
    __syncthreads();

    // epilogue: 16 dsts x (8 lanes x 4 channels); threads 128..255 idle
    {
        const int li8 = threadIdx.x & 7;
        const int dl  = threadIdx.x >> 3;
        const int n   = bin * DPB + dl;
        if (dl < DPB && n < NN) {
            const uint32_t* ar = &agg[dl * ASTR + li8 * 4];
            float av[4];
#pragma unroll
            for (int qq = 0; qq < 4; ++qq) {
                uint32_t u = ar[qq];
                av[qq] = (u == SENT) ? 0.f : unmap_f(u);
            }
            const float* xr = x + (size_t)n * INF_;
            float4 xa = *reinterpret_cast<const float4*>(xr);
            float4 xb = *reinterpret_cast<const float4*>(xr + 4);
            float4 xc = *reinterpret_cast<const float4*>(xr + 8);
            float4 xd = *reinterpret_cast<const float4*>(xr + 12);
            float xv[INF_] = {xa.x,xa.y,xa.z,xa.w, xb.x,xb.y,xb.z,xb.w,
                              xc.x,xc.y,xc.z,xc.w, xd.x,xd.y,xd.z,xd.w};
            float ov[4];
#pragma unroll
            for (int qq = 0; qq < 4; ++qq) {
                int oc = li8 * 4 + qq;
                float tv = av[qq] + bs[oc];
#pragma unroll
                for (int i = 0; i < INF_; ++i) tv = fmaf(xv[i], rs[i * OUTF + oc], tv);
                ov[qq] = (tv > 0.f) ? tv : expm1f(tv);   // ELU alpha=1
            }
            float lg[NC];
#pragma unroll
            for (int cc = 0; cc < NC; ++cc) {
                float tv = 0.f;
#pragma unroll
                for (int qq = 0; qq < 4; ++qq) tv = fmaf(ov[qq], fws[(li8 * 4 + qq) * NC + cc], tv);
                lg[cc] = tv;
            }
#pragma unroll
            for (int m = 1; m <= 4; m <<= 1) {
#pragma unroll
                for (int cc = 0; cc < NC; ++cc) lg[cc] += __shfl_xor(lg[cc], m);
            }
#pragma unroll
            for (int cc = 0; cc < NC; ++cc) lg[cc] += fbs[cc];

            float mx = lg[0];
#pragma unroll
            for (int cc = 1; cc < NC; ++cc) mx = fmaxf(mx, lg[cc]);
            float ssum = 0.f;
#pragma unroll
            for (int cc = 0; cc < NC; ++cc) ssum += expf(lg[cc] - mx);
            float lse = mx + logf(ssum);

            float* orow = out + (size_t)n * NC;
            orow[li8] = lg[li8] - lse;
            if (li8 < 2) orow[8 + li8] = lg[8 + li8] - lse;
        }
    }
}

extern "C" void kernel_launch(void* const* d_in, const int* in_sizes, int n_in,
                              void* d_out, int out_size, void* d_ws, size_t ws_size,
                              hipStream_t stream) {
    const float* x    = (const float*)d_in[0];
    const float* ea   = (const float*)d_in[1];
    const int*   ei   = (const int*)d_in[2];
    const float* w1   = (const float*)d_in[3];
    const float* b1   = (const float*)d_in[4];
    const float* w2   = (const float*)d_in[5];
    const float* b2   = (const float*)d_in[6];
    const float* root = (const float*)d_in[7];
    const float* bias = (const float*)d_in[8];
    const float* fcw  = (const float*)d_in[9];
    const float* fcb  = (const float*)d_in[10];
    float* out = (float*)d_out;

    size_t off = 0;
    auto alloc = [&](size_t bytes) {
        void* p = (char*)d_ws + off;
        off += (bytes + 255) & ~(size_t)255;
        return p;
    };
    uint32_t* G2       = (uint32_t*)alloc((size_t)QG * 256 * 4);               // 2 MB
    uint32_t* xh       = (uint32_t*)alloc((size_t)NN * INF_ * 2);              // 1.6 MB
    uint32_t* H        = (uint32_t*)alloc((size_t)NB * NBLK * 4);              // 2.45 MB
    uint32_t* Bp       = (uint32_t*)alloc((size_t)NB * NBLK * 4);              // 2.45 MB
    uint32_t* tot      = (uint32_t*)alloc((size_t)NB * 4);
    uint32_t* bstart   = (uint32_t*)alloc((size_t)(NB + 1) * 4);
    uint32_t* sorted   = (uint32_t*)alloc((size_t)NE * 4);                     // 3.2 MB

    prep_k<<<GB_PREP + GB_HIST + GB_XH, 256, 0, stream>>>(w1, b1, w2, b2, x, ei, G2, xh, H);
    colsum_k<<<(NB * 64 + 255) / 256, 256, 0, stream>>>(H, Bp, tot);
    binscan_k<<<1, 256, 0, stream>>>(tot, bstart);
    scatter_k<<<NBLK, 256, 0, stream>>>(ei, ea, Bp, bstart, sorted);
    fused_k<<<NB, 256, 0, stream>>>(sorted, bstart, x, xh, G2, root, bias, fcw, fcb, out);
}